// Round 5
// baseline (5752.026 us; speedup 1.0000x reference)
//
#include <hip/hip_runtime.h>
#include <hip/hip_bf16.h>

#define BB 4
#define SS 1024
#define HH 1024
#define NHH 16
#define DD 64
#define MAXPOS 1024

// ---------------------------------------------------------------------------
// Kernel 1: fused QKV projection.  out = x @ W^T + b, scattered to [B,NH,S,D].
// x:[4096,1024] fp32 row-major, W:[1024,1024] fp32 row-major (k contiguous).
// grid (16, 64, 3), block 256.  64x64 tile, BK=32, 4x4 micro-tile per thread.
// ---------------------------------------------------------------------------
__global__ void qkv_gemm(const float* __restrict__ x,
                         const float* __restrict__ Wq, const float* __restrict__ bq,
                         const float* __restrict__ Wk, const float* __restrict__ bk,
                         const float* __restrict__ Wv, const float* __restrict__ bv,
                         float* __restrict__ q, float* __restrict__ k,
                         float* __restrict__ v)
{
    const int which = blockIdx.z;
    const float* __restrict__ W    = (which == 0) ? Wq : (which == 1) ? Wk : Wv;
    const float* __restrict__ bias = (which == 0) ? bq : (which == 1) ? bk : bv;
    float* __restrict__ out        = (which == 0) ? q  : (which == 1) ? k  : v;

    __shared__ float As[64][33];
    __shared__ float Bs[64][33];

    const int tid  = threadIdx.x;
    const int row0 = blockIdx.y * 64;
    const int col0 = blockIdx.x * 64;
    const int tr = tid / 16, tc = tid % 16;

    float acc[4][4] = {};

    const int lr = tid / 4;
    const int lk = (tid % 4) * 8;

    for (int k0 = 0; k0 < 1024; k0 += 32) {
        const float4* ap = (const float4*)(x + (row0 + lr) * 1024 + k0 + lk);
        const float4* bp = (const float4*)(W + (col0 + lr) * 1024 + k0 + lk);
        float4 a0 = ap[0], a1 = ap[1];
        float4 b0 = bp[0], b1 = bp[1];
        As[lr][lk + 0] = a0.x; As[lr][lk + 1] = a0.y; As[lr][lk + 2] = a0.z; As[lr][lk + 3] = a0.w;
        As[lr][lk + 4] = a1.x; As[lr][lk + 5] = a1.y; As[lr][lk + 6] = a1.z; As[lr][lk + 7] = a1.w;
        Bs[lr][lk + 0] = b0.x; Bs[lr][lk + 1] = b0.y; Bs[lr][lk + 2] = b0.z; Bs[lr][lk + 3] = b0.w;
        Bs[lr][lk + 4] = b1.x; Bs[lr][lk + 5] = b1.y; Bs[lr][lk + 6] = b1.z; Bs[lr][lk + 7] = b1.w;
        __syncthreads();
#pragma unroll
        for (int kk = 0; kk < 32; kk++) {
            float a[4], bw[4];
#pragma unroll
            for (int i = 0; i < 4; i++) a[i] = As[tr * 4 + i][kk];
#pragma unroll
            for (int j = 0; j < 4; j++) bw[j] = Bs[tc * 4 + j][kk];
#pragma unroll
            for (int i = 0; i < 4; i++)
#pragma unroll
                for (int j = 0; j < 4; j++) acc[i][j] += a[i] * bw[j];
        }
        __syncthreads();
    }

#pragma unroll
    for (int i = 0; i < 4; i++) {
        const int gi = row0 + tr * 4 + i;       // = b*S + l
        const int b_ = gi >> 10, l = gi & 1023;
#pragma unroll
        for (int j = 0; j < 4; j++) {
            const int gj = col0 + tc * 4 + j;   // = h*64 + d
            const int h_ = gj >> 6, d_ = gj & 63;
            out[(((b_ * NHH) + h_) * SS + l) * DD + d_] = acc[i][j] + bias[gj];
        }
    }
}

// ---------------------------------------------------------------------------
// Kernel 2: attention, one block per (b,h,l) score row.
// scores[r] = (q.k[r] + q.E[l-r+1023] + k[r].E[l-r+1023]) / 8 + mask[b,r]
// softmax over r, then ctx[d] = sum_r p[r] v[r,d], written fp32 to d_out
// in [B,S,H] layout.  grid (1024, 16, 4), block 256.
// ---------------------------------------------------------------------------
__global__ void attn(const float* __restrict__ q, const float* __restrict__ k,
                     const float* __restrict__ v, const float* __restrict__ dist_emb,
                     const float* __restrict__ mask, float* __restrict__ ctx)
{
    const int l = blockIdx.x, h = blockIdx.y, b = blockIdx.z;
    const int tid = threadIdx.x;

    const float* __restrict__ qrow  = q + ((b * NHH + h) * SS + l) * DD;
    const float* __restrict__ kbase = k + (b * NHH + h) * SS * DD;
    const float* __restrict__ vbase = v + (b * NHH + h) * SS * DD;

    __shared__ float qs[64];
    __shared__ float sc[1024];
    __shared__ float red[256];

    if (tid < 64) qs[tid] = qrow[tid];
    __syncthreads();

    for (int r = tid; r < 1024; r += 256) {
        const float* kr = kbase + r * 64;
        const float* er = dist_emb + (l - r + MAXPOS - 1) * 64;
        float s1 = 0.f, s2 = 0.f, s3 = 0.f;
#pragma unroll 8
        for (int d = 0; d < 64; d++) {
            float e  = er[d];
            float kk = kr[d];
            float qq = qs[d];
            s1 += qq * kk;
            s2 += qq * e;
            s3 += kk * e;
        }
        sc[r] = (s1 + s2 + s3) * 0.125f + mask[b * SS + r];
    }
    __syncthreads();

    // --- max reduce ---
    float m = -1e30f;
    for (int r = tid; r < 1024; r += 256) m = fmaxf(m, sc[r]);
    red[tid] = m;
    __syncthreads();
    for (int s = 128; s > 0; s >>= 1) {
        if (tid < s) red[tid] = fmaxf(red[tid], red[tid + s]);
        __syncthreads();
    }
    m = red[0];
    __syncthreads();

    // --- exp + sum reduce ---
    float sum = 0.f;
    for (int r = tid; r < 1024; r += 256) {
        float e = expf(sc[r] - m);
        sc[r] = e;
        sum += e;
    }
    red[tid] = sum;
    __syncthreads();
    for (int s = 128; s > 0; s >>= 1) {
        if (tid < s) red[tid] += red[tid + s];
        __syncthreads();
    }
    const float inv = 1.0f / red[0];
    __syncthreads();

    // --- ctx: thread (rc,d) accumulates 256 r's for one d ---
    const int d_ = tid & 63, rc = tid >> 6;
    float acc = 0.f;
    const int rbeg = rc * 256;
    for (int r = rbeg; r < rbeg + 256; r++) acc += sc[r] * vbase[r * 64 + d_];
    __syncthreads();
    red[tid] = acc;
    __syncthreads();
    if (tid < 64) {
        float t = red[tid] + red[tid + 64] + red[tid + 128] + red[tid + 192];
        ctx[(b * SS + l) * HH + h * 64 + tid] = t * inv;
    }
}

// ---------------------------------------------------------------------------
// Kernel 3: output projection + residual.  y = ctx @ Wo^T + bo + x  (fp32 out)
// ctx fp32 in d_out; y -> ws (dead q region).  grid (16, 64), block 256.
// ---------------------------------------------------------------------------
__global__ void out_gemm(const float* __restrict__ ctx, const float* __restrict__ Wo,
                         const float* __restrict__ bo, const float* __restrict__ x,
                         float* __restrict__ y)
{
    __shared__ float As[64][33];
    __shared__ float Bs[64][33];

    const int tid  = threadIdx.x;
    const int row0 = blockIdx.y * 64;
    const int col0 = blockIdx.x * 64;
    const int tr = tid / 16, tc = tid % 16;

    float acc[4][4] = {};
    const int lr = tid / 4;
    const int lk = (tid % 4) * 8;

    for (int k0 = 0; k0 < 1024; k0 += 32) {
        const float4* ap = (const float4*)(ctx + (row0 + lr) * 1024 + k0 + lk);
        const float4* bp = (const float4*)(Wo + (col0 + lr) * 1024 + k0 + lk);
        float4 a0 = ap[0], a1 = ap[1];
        float4 b0 = bp[0], b1 = bp[1];
        As[lr][lk + 0] = a0.x; As[lr][lk + 1] = a0.y; As[lr][lk + 2] = a0.z; As[lr][lk + 3] = a0.w;
        As[lr][lk + 4] = a1.x; As[lr][lk + 5] = a1.y; As[lr][lk + 6] = a1.z; As[lr][lk + 7] = a1.w;
        Bs[lr][lk + 0] = b0.x; Bs[lr][lk + 1] = b0.y; Bs[lr][lk + 2] = b0.z; Bs[lr][lk + 3] = b0.w;
        Bs[lr][lk + 4] = b1.x; Bs[lr][lk + 5] = b1.y; Bs[lr][lk + 6] = b1.z; Bs[lr][lk + 7] = b1.w;
        __syncthreads();
#pragma unroll
        for (int kk = 0; kk < 32; kk++) {
            float a[4], bw[4];
#pragma unroll
            for (int i = 0; i < 4; i++) a[i] = As[tr * 4 + i][kk];
#pragma unroll
            for (int j = 0; j < 4; j++) bw[j] = Bs[tc * 4 + j][kk];
#pragma unroll
            for (int i = 0; i < 4; i++)
#pragma unroll
                for (int j = 0; j < 4; j++) acc[i][j] += a[i] * bw[j];
        }
        __syncthreads();
    }

#pragma unroll
    for (int i = 0; i < 4; i++) {
        const int gi = row0 + tr * 4 + i;
#pragma unroll
        for (int j = 0; j < 4; j++) {
            const int gj = col0 + tc * 4 + j;
            y[gi * 1024 + gj] = acc[i][j] + bo[gj] + x[gi * 1024 + gj];
        }
    }
}

// ---------------------------------------------------------------------------
// Kernel 4: LayerNorm per row, fp32 output to d_out.  grid 4096, block 256.
// ---------------------------------------------------------------------------
__global__ void layernorm(const float* __restrict__ y, const float* __restrict__ g,
                          const float* __restrict__ beta, float* __restrict__ out)
{
    const int row = blockIdx.x;
    const float* yr = y + row * 1024;
    const int tid = threadIdx.x;

    __shared__ float red[256];
    __shared__ float red2[256];

    float s = 0.f, s2 = 0.f;
    float vals[4];
#pragma unroll
    for (int c = 0; c < 4; c++) {
        float t = yr[tid + c * 256];
        vals[c] = t;
        s += t;
        s2 += t * t;
    }
    red[tid] = s;
    red2[tid] = s2;
    __syncthreads();
    for (int st = 128; st > 0; st >>= 1) {
        if (tid < st) { red[tid] += red[tid + st]; red2[tid] += red2[tid + st]; }
        __syncthreads();
    }
    const float mu  = red[0] * (1.0f / 1024.0f);
    const float var = red2[0] * (1.0f / 1024.0f) - mu * mu;
    const float rs  = rsqrtf(var + 1e-12f);

#pragma unroll
    for (int c = 0; c < 4; c++) {
        const int j = tid + c * 256;
        out[row * 1024 + j] = (vals[c] - mu) * rs * g[j] + beta[j];
    }
}

// ---------------------------------------------------------------------------
extern "C" void kernel_launch(void* const* d_in, const int* in_sizes, int n_in,
                              void* d_out, int out_size, void* d_ws, size_t ws_size,
                              hipStream_t stream)
{
    const float* x    = (const float*)d_in[0];
    const float* mask = (const float*)d_in[1];
    const float* Wq   = (const float*)d_in[2];
    const float* bq   = (const float*)d_in[3];
    const float* Wk   = (const float*)d_in[4];
    const float* bk   = (const float*)d_in[5];
    const float* Wv   = (const float*)d_in[6];
    const float* bv   = (const float*)d_in[7];
    const float* dist = (const float*)d_in[8];
    const float* Wo   = (const float*)d_in[9];
    const float* bo   = (const float*)d_in[10];
    const float* g    = (const float*)d_in[11];
    const float* be   = (const float*)d_in[12];

    // ws (fp32): q | k | v  = 48 MB.  ctx lives in d_out (fp32, 16 MB);
    // y reuses the dead q region; final LayerNorm overwrites d_out.
    float* ws   = (float*)d_ws;
    float* q    = ws;
    float* k    = ws + 1 * 4194304;
    float* v    = ws + 2 * 4194304;
    float* ctxb = (float*)d_out;
    float* y    = q;  // q dead after attn

    qkv_gemm<<<dim3(16, 64, 3), 256, 0, stream>>>(x, Wq, bq, Wk, bk, Wv, bv, q, k, v);
    attn<<<dim3(1024, 16, 4), 256, 0, stream>>>(q, k, v, dist, mask, ctxb);
    out_gemm<<<dim3(16, 64), 256, 0, stream>>>(ctxb, Wo, bo, x, y);
    layernorm<<<4096, 256, 0, stream>>>(y, g, be, (float*)d_out);
}

// Round 6
// 1147.455 us; speedup vs baseline: 5.0129x; 5.0129x over previous
//
#include <hip/hip_runtime.h>
#include <hip/hip_bf16.h>

#define BB 4
#define SS 1024
#define HH 1024
#define NHH 16
#define DD 64
#define MAXPOS 1024

typedef __hip_bfloat16 bf16;
typedef unsigned short ushort_t;
typedef __attribute__((ext_vector_type(8))) short short8;
typedef __attribute__((ext_vector_type(4))) float f32x4;

#define MFMA_16x16x32(a, b, c) __builtin_amdgcn_mfma_f32_16x16x32_bf16((a), (b), (c), 0, 0, 0)

__device__ __forceinline__ float bu2f(ushort_t u) {
    union { unsigned int i; float f; } c; c.i = ((unsigned int)u) << 16; return c.f;
}
__device__ __forceinline__ ushort_t f2bu(float f) {
    __hip_bfloat16 h = __float2bfloat16(f);
    return *reinterpret_cast<ushort_t*>(&h);
}

// ---------------------------------------------------------------------------
// Kernel 0: convert dist_emb fp32 [2047,64] -> bf16 [2048,64] (row 2047 = 0).
// ---------------------------------------------------------------------------
__global__ void conv_E(const float* __restrict__ dist, ushort_t* __restrict__ Eb)
{
    const int idx = blockIdx.x * 256 + threadIdx.x;   // grid 512 -> 131072
    float v = (idx < 2047 * 64) ? dist[idx] : 0.0f;
    Eb[idx] = f2bu(v);
}

// ---------------------------------------------------------------------------
// Kernel 1: fused QKV projection.  out = x @ W^T + b -> bf16 [B,NH,S,D].
// grid (16, 64, 3), block 256.  (fp32 VALU; MFMA-ize in a later round.)
// ---------------------------------------------------------------------------
__global__ void qkv_gemm(const float* __restrict__ x,
                         const float* __restrict__ Wq, const float* __restrict__ bq,
                         const float* __restrict__ Wk, const float* __restrict__ bk,
                         const float* __restrict__ Wv, const float* __restrict__ bv,
                         bf16* __restrict__ q, bf16* __restrict__ k,
                         bf16* __restrict__ v)
{
    const int which = blockIdx.z;
    const float* __restrict__ W    = (which == 0) ? Wq : (which == 1) ? Wk : Wv;
    const float* __restrict__ bias = (which == 0) ? bq : (which == 1) ? bk : bv;
    bf16* __restrict__ out         = (which == 0) ? q  : (which == 1) ? k  : v;

    __shared__ float As[64][33];
    __shared__ float Bs[64][33];

    const int tid  = threadIdx.x;
    const int row0 = blockIdx.y * 64;
    const int col0 = blockIdx.x * 64;
    const int tr = tid / 16, tc = tid % 16;

    float acc[4][4] = {};
    const int lr = tid / 4;
    const int lk = (tid % 4) * 8;

    for (int k0 = 0; k0 < 1024; k0 += 32) {
        const float4* ap = (const float4*)(x + (row0 + lr) * 1024 + k0 + lk);
        const float4* bp = (const float4*)(W + (col0 + lr) * 1024 + k0 + lk);
        float4 a0 = ap[0], a1 = ap[1];
        float4 b0 = bp[0], b1 = bp[1];
        As[lr][lk + 0] = a0.x; As[lr][lk + 1] = a0.y; As[lr][lk + 2] = a0.z; As[lr][lk + 3] = a0.w;
        As[lr][lk + 4] = a1.x; As[lr][lk + 5] = a1.y; As[lr][lk + 6] = a1.z; As[lr][lk + 7] = a1.w;
        Bs[lr][lk + 0] = b0.x; Bs[lr][lk + 1] = b0.y; Bs[lr][lk + 2] = b0.z; Bs[lr][lk + 3] = b0.w;
        Bs[lr][lk + 4] = b1.x; Bs[lr][lk + 5] = b1.y; Bs[lr][lk + 6] = b1.z; Bs[lr][lk + 7] = b1.w;
        __syncthreads();
#pragma unroll
        for (int kk = 0; kk < 32; kk++) {
            float a[4], bw[4];
#pragma unroll
            for (int i = 0; i < 4; i++) a[i] = As[tr * 4 + i][kk];
#pragma unroll
            for (int j = 0; j < 4; j++) bw[j] = Bs[tc * 4 + j][kk];
#pragma unroll
            for (int i = 0; i < 4; i++)
#pragma unroll
                for (int j = 0; j < 4; j++) acc[i][j] += a[i] * bw[j];
        }
        __syncthreads();
    }

#pragma unroll
    for (int i = 0; i < 4; i++) {
        const int gi = row0 + tr * 4 + i;       // = b*S + l
        const int b_ = gi >> 10, l = gi & 1023;
#pragma unroll
        for (int j = 0; j < 4; j++) {
            const int gj = col0 + tc * 4 + j;   // = h*64 + d
            const int h_ = gj >> 6, d_ = gj & 63;
            out[(((b_ * NHH) + h_) * SS + l) * DD + d_] =
                __float2bfloat16(acc[i][j] + bias[gj]);
        }
    }
}

// ---------------------------------------------------------------------------
// Kernel 2: MFMA flash attention with relative_key_query bias.
// grid (16 l-tiles, NH, B), block 256 (4 waves).  Each wg: Q tile [64,64],
// loop over 16 r-tiles.  Per tile:
//   S1 = Q K^T (MFMA);  QE = Q E_win^T, KE = K E_win^T (MFMA -> LDS bf16);
//   S[i,j] = (S1 + QE[i,i-j+63] + KE[j,i-j+63])/8 + mask[b,r]
//   online softmax (per-quad shuffle reductions), P -> LDS bf16, O += P V.
// ctx written fp32 [B,S,H] to d_out.
// ---------------------------------------------------------------------------
__global__ __launch_bounds__(256)
void attn_mfma(const ushort_t* __restrict__ qb, const ushort_t* __restrict__ kb,
               const ushort_t* __restrict__ vb, const ushort_t* __restrict__ Eb,
               const float* __restrict__ mask, float* __restrict__ ctx)
{
    const int l0 = blockIdx.x * 64;
    const int h  = blockIdx.y, b = blockIdx.z;
    const int tid  = threadIdx.x;
    const int w    = tid >> 6;
    const int lane = tid & 63;
    const int quad = lane >> 4, lq = lane & 15;

    // LDS: 2*16768 + 2*9216 = 51,968 B -> 3 wg/CU
    __shared__ __align__(16) ushort_t QEs[64 * 131];
    __shared__ __align__(16) ushort_t KEs[64 * 131];
    __shared__ __align__(16) ushort_t Ps [64 * 72];
    __shared__ __align__(16) ushort_t VTs[64 * 72];

    const ushort_t* qbh = qb + ((size_t)(b * NHH + h) * SS) * DD;
    const ushort_t* kbh = kb + ((size_t)(b * NHH + h) * SS) * DD;
    const ushort_t* vbh = vb + ((size_t)(b * NHH + h) * SS) * DD;

    // Q A-frags for this wave's 16 l-rows (A[m=lane&15][k=quad*8+j], K=32 x2)
    short8 qa0, qa1;
    {
        const ushort_t* qrow = qbh + (l0 + w * 16 + lq) * DD + quad * 8;
        qa0 = *(const short8*)(qrow);
        qa1 = *(const short8*)(qrow + 32);
    }

    f32x4 Oacc[4];
#pragma unroll
    for (int dt = 0; dt < 4; dt++) Oacc[dt] = (f32x4){0.f, 0.f, 0.f, 0.f};
    float mrow[4] = {-3e38f, -3e38f, -3e38f, -3e38f};
    float lrow[4] = {0.f, 0.f, 0.f, 0.f};

    for (int rt = 0; rt < 16; rt++) {
        const int r0   = rt * 64;
        const int dmin = l0 - r0 + 960;   // window [dmin, dmin+127] in [0,2047]

        __syncthreads();   // (C) prior PV reads done before LDS overwrite

        // --- stage V^T tile: VTs[d][r], 64x64, row stride 72 halves ---
        for (int s = tid; s < 512; s += 256) {
            const int r = s >> 3, d0 = (s & 7) * 8;
            short8 vv = *(const short8*)(vbh + (r0 + r) * DD + d0);
#pragma unroll
            for (int e = 0; e < 8; e++) VTs[(d0 + e) * 72 + r] = (ushort_t)vv[e];
        }

        // --- K fragments: B-operand for S1 (col-tile ct), A-operand (ct==w) ---
        short8 kf[4][2];
#pragma unroll
        for (int ct = 0; ct < 4; ct++) {
            const ushort_t* krow = kbh + (r0 + ct * 16 + lq) * DD + quad * 8;
            kf[ct][0] = *(const short8*)(krow);
            kf[ct][1] = *(const short8*)(krow + 32);
        }

        // --- QE and KE via MFMA, store bf16 to LDS (row stride 131) ---
#pragma unroll
        for (int tt = 0; tt < 8; tt++) {
            const ushort_t* erow = Eb + (dmin + tt * 16 + lq) * DD + quad * 8;
            short8 eb0 = *(const short8*)(erow);
            short8 eb1 = *(const short8*)(erow + 32);
            f32x4 qe = (f32x4){0.f, 0.f, 0.f, 0.f};
            f32x4 ke = (f32x4){0.f, 0.f, 0.f, 0.f};
            qe = MFMA_16x16x32(qa0, eb0, qe);
            qe = MFMA_16x16x32(qa1, eb1, qe);
            ke = MFMA_16x16x32(kf[w][0], eb0, ke);
            ke = MFMA_16x16x32(kf[w][1], eb1, ke);
#pragma unroll
            for (int g = 0; g < 4; g++) {
                const int row = w * 16 + quad * 4 + g;
                QEs[row * 131 + tt * 16 + lq] = f2bu(qe[g]);
                KEs[row * 131 + tt * 16 + lq] = f2bu(ke[g]);
            }
        }

        // --- S1 = Q K^T for this wave's row-slab [16 x 64] ---
        f32x4 s1[4];
#pragma unroll
        for (int ct = 0; ct < 4; ct++) {
            f32x4 a = (f32x4){0.f, 0.f, 0.f, 0.f};
            a = MFMA_16x16x32(qa0, kf[ct][0], a);
            a = MFMA_16x16x32(qa1, kf[ct][1], a);
            s1[ct] = a;
        }

        __syncthreads();   // (A) QEs/KEs/VTs visible

        // --- assemble scores + online softmax ---
        float p[4][4];
        float tmax[4] = {-3e38f, -3e38f, -3e38f, -3e38f};
#pragma unroll
        for (int ct = 0; ct < 4; ct++) {
            const int j_wg = ct * 16 + lq;
            const float mk = mask[b * SS + r0 + j_wg];
#pragma unroll
            for (int g = 0; g < 4; g++) {
                const int i_wg = w * 16 + quad * 4 + g;
                const int t = i_wg - j_wg + 63;   // in [0,126]
                float s = (s1[ct][g] + bu2f(QEs[i_wg * 131 + t])
                                     + bu2f(KEs[j_wg * 131 + t])) * 0.125f + mk;
                p[ct][g] = s;
                tmax[g] = fmaxf(tmax[g], s);
            }
        }
#pragma unroll
        for (int g = 0; g < 4; g++) {   // row-max across 16 lanes of the quad
            float v = tmax[g];
            v = fmaxf(v, __shfl_xor(v, 1));
            v = fmaxf(v, __shfl_xor(v, 2));
            v = fmaxf(v, __shfl_xor(v, 4));
            v = fmaxf(v, __shfl_xor(v, 8));
            tmax[g] = v;
        }
        float psum[4] = {0.f, 0.f, 0.f, 0.f};
        float alpha[4];
#pragma unroll
        for (int g = 0; g < 4; g++) {
            const float mnew = fmaxf(mrow[g], tmax[g]);
            alpha[g] = __expf(mrow[g] - mnew);
            mrow[g] = mnew;
        }
#pragma unroll
        for (int ct = 0; ct < 4; ct++)
#pragma unroll
            for (int g = 0; g < 4; g++) {
                const float e = __expf(p[ct][g] - mrow[g]);
                p[ct][g] = e;
                psum[g] += e;
            }
#pragma unroll
        for (int g = 0; g < 4; g++) {   // row-sum across quad lanes
            float v = psum[g];
            v += __shfl_xor(v, 1);
            v += __shfl_xor(v, 2);
            v += __shfl_xor(v, 4);
            v += __shfl_xor(v, 8);
            lrow[g] = lrow[g] * alpha[g] + v;
        }
#pragma unroll
        for (int dt = 0; dt < 4; dt++)
#pragma unroll
            for (int g = 0; g < 4; g++) Oacc[dt][g] *= alpha[g];
        // write P (bf16) to LDS, row stride 72
#pragma unroll
        for (int ct = 0; ct < 4; ct++)
#pragma unroll
            for (int g = 0; g < 4; g++)
                Ps[(w * 16 + quad * 4 + g) * 72 + ct * 16 + lq] = f2bu(p[ct][g]);

        __syncthreads();   // (B) Ps ready

        // --- O += P V  (A from Ps, B from VTs) ---
        short8 pa0, pa1;
        {
            const ushort_t* prow = Ps + (w * 16 + lq) * 72 + quad * 8;
            pa0 = *(const short8*)(prow);
            pa1 = *(const short8*)(prow + 32);
        }
#pragma unroll
        for (int dt = 0; dt < 4; dt++) {
            const ushort_t* vtr = VTs + (dt * 16 + lq) * 72 + quad * 8;
            short8 vb0 = *(const short8*)(vtr);
            short8 vb1 = *(const short8*)(vtr + 32);
            Oacc[dt] = MFMA_16x16x32(pa0, vb0, Oacc[dt]);
            Oacc[dt] = MFMA_16x16x32(pa1, vb1, Oacc[dt]);
        }
    }

    // --- epilogue: ctx[b, l, h*64+d] = O / l ---
#pragma unroll
    for (int g = 0; g < 4; g++) {
        const int l = l0 + w * 16 + quad * 4 + g;
        const float invl = 1.0f / lrow[g];
#pragma unroll
        for (int dt = 0; dt < 4; dt++)
            ctx[(size_t)(b * SS + l) * HH + h * DD + dt * 16 + lq] = Oacc[dt][g] * invl;
    }
}

// ---------------------------------------------------------------------------
// Kernel 3: output projection + residual.  y = ctx @ Wo^T + bo + x  (fp32)
// ---------------------------------------------------------------------------
__global__ void out_gemm(const float* __restrict__ ctx, const float* __restrict__ Wo,
                         const float* __restrict__ bo, const float* __restrict__ x,
                         float* __restrict__ y)
{
    __shared__ float As[64][33];
    __shared__ float Bs[64][33];

    const int tid  = threadIdx.x;
    const int row0 = blockIdx.y * 64;
    const int col0 = blockIdx.x * 64;
    const int tr = tid / 16, tc = tid % 16;

    float acc[4][4] = {};
    const int lr = tid / 4;
    const int lk = (tid % 4) * 8;

    for (int k0 = 0; k0 < 1024; k0 += 32) {
        const float4* ap = (const float4*)(ctx + (row0 + lr) * 1024 + k0 + lk);
        const float4* bp = (const float4*)(Wo + (col0 + lr) * 1024 + k0 + lk);
        float4 a0 = ap[0], a1 = ap[1];
        float4 b0 = bp[0], b1 = bp[1];
        As[lr][lk + 0] = a0.x; As[lr][lk + 1] = a0.y; As[lr][lk + 2] = a0.z; As[lr][lk + 3] = a0.w;
        As[lr][lk + 4] = a1.x; As[lr][lk + 5] = a1.y; As[lr][lk + 6] = a1.z; As[lr][lk + 7] = a1.w;
        Bs[lr][lk + 0] = b0.x; Bs[lr][lk + 1] = b0.y; Bs[lr][lk + 2] = b0.z; Bs[lr][lk + 3] = b0.w;
        Bs[lr][lk + 4] = b1.x; Bs[lr][lk + 5] = b1.y; Bs[lr][lk + 6] = b1.z; Bs[lr][lk + 7] = b1.w;
        __syncthreads();
#pragma unroll
        for (int kk = 0; kk < 32; kk++) {
            float a[4], bw[4];
#pragma unroll
            for (int i = 0; i < 4; i++) a[i] = As[tr * 4 + i][kk];
#pragma unroll
            for (int j = 0; j < 4; j++) bw[j] = Bs[tc * 4 + j][kk];
#pragma unroll
            for (int i = 0; i < 4; i++)
#pragma unroll
                for (int j = 0; j < 4; j++) acc[i][j] += a[i] * bw[j];
        }
        __syncthreads();
    }

#pragma unroll
    for (int i = 0; i < 4; i++) {
        const int gi = row0 + tr * 4 + i;
#pragma unroll
        for (int j = 0; j < 4; j++) {
            const int gj = col0 + tc * 4 + j;
            y[gi * 1024 + gj] = acc[i][j] + bo[gj] + x[gi * 1024 + gj];
        }
    }
}

// ---------------------------------------------------------------------------
// Kernel 4: LayerNorm per row, fp32 output to d_out.  grid 4096, block 256.
// ---------------------------------------------------------------------------
__global__ void layernorm(const float* __restrict__ y, const float* __restrict__ g,
                          const float* __restrict__ beta, float* __restrict__ out)
{
    const int row = blockIdx.x;
    const float* yr = y + row * 1024;
    const int tid = threadIdx.x;

    __shared__ float red[256];
    __shared__ float red2[256];

    float s = 0.f, s2 = 0.f;
    float vals[4];
#pragma unroll
    for (int c = 0; c < 4; c++) {
        float t = yr[tid + c * 256];
        vals[c] = t;
        s += t;
        s2 += t * t;
    }
    red[tid] = s;
    red2[tid] = s2;
    __syncthreads();
    for (int st = 128; st > 0; st >>= 1) {
        if (tid < st) { red[tid] += red[tid + st]; red2[tid] += red2[tid + st]; }
        __syncthreads();
    }
    const float mu  = red[0] * (1.0f / 1024.0f);
    const float var = red2[0] * (1.0f / 1024.0f) - mu * mu;
    const float rs  = rsqrtf(var + 1e-12f);

#pragma unroll
    for (int c = 0; c < 4; c++) {
        const int j = tid + c * 256;
        out[row * 1024 + j] = (vals[c] - mu) * rs * g[j] + beta[j];
    }
}

// ---------------------------------------------------------------------------
extern "C" void kernel_launch(void* const* d_in, const int* in_sizes, int n_in,
                              void* d_out, int out_size, void* d_ws, size_t ws_size,
                              hipStream_t stream)
{
    const float* x    = (const float*)d_in[0];
    const float* mask = (const float*)d_in[1];
    const float* Wq   = (const float*)d_in[2];
    const float* bq   = (const float*)d_in[3];
    const float* Wk   = (const float*)d_in[4];
    const float* bk   = (const float*)d_in[5];
    const float* Wv   = (const float*)d_in[6];
    const float* bv   = (const float*)d_in[7];
    const float* dist = (const float*)d_in[8];
    const float* Wo   = (const float*)d_in[9];
    const float* bo   = (const float*)d_in[10];
    const float* g    = (const float*)d_in[11];
    const float* be   = (const float*)d_in[12];

    // ws bytes: qb[0,8M) kb[8M,16M) vb[16M,24M) Eb[24M,24M+256K) y[28M,44M)
    // total 44 MB <= proven-safe 48 MB.
    char* wsb = (char*)d_ws;
    bf16*     qbu = (bf16*)(wsb);
    bf16*     kbu = (bf16*)(wsb + (8u << 20));
    bf16*     vbu = (bf16*)(wsb + (16u << 20));
    ushort_t* Eb  = (ushort_t*)(wsb + (24u << 20));
    float*    y   = (float*)(wsb + (28u << 20));
    float*    ctxb = (float*)d_out;

    conv_E<<<512, 256, 0, stream>>>(dist, Eb);
    qkv_gemm<<<dim3(16, 64, 3), 256, 0, stream>>>(x, Wq, bq, Wk, bk, Wv, bv,
                                                  qbu, kbu, vbu);
    attn_mfma<<<dim3(16, 16, 4), 256, 0, stream>>>((const ushort_t*)qbu,
                                                   (const ushort_t*)kbu,
                                                   (const ushort_t*)vbu,
                                                   Eb, mask, ctxb);
    out_gemm<<<dim3(16, 64), 256, 0, stream>>>(ctxb, Wo, bo, x, y);
    layernorm<<<4096, 256, 0, stream>>>(y, g, be, (float*)d_out);
}

// Round 7
// 677.076 us; speedup vs baseline: 8.4954x; 1.6947x over previous
//
#include <hip/hip_runtime.h>
#include <hip/hip_bf16.h>

#define BB 4
#define SS 1024
#define HH 1024
#define NHH 16
#define DD 64
#define MAXPOS 1024

typedef __hip_bfloat16 bf16;
typedef unsigned short ushort_t;
typedef __attribute__((ext_vector_type(8))) short short8;
typedef __attribute__((ext_vector_type(4))) float f32x4;
typedef __attribute__((ext_vector_type(4))) unsigned short us4;

#define MFMA_16x16x32(a, b, c) __builtin_amdgcn_mfma_f32_16x16x32_bf16((a), (b), (c), 0, 0, 0)

__device__ __forceinline__ float bu2f(ushort_t u) {
    union { unsigned int i; float f; } c; c.i = ((unsigned int)u) << 16; return c.f;
}
__device__ __forceinline__ ushort_t f2bu(float f) {
    __hip_bfloat16 h = __float2bfloat16(f);
    return *reinterpret_cast<ushort_t*>(&h);
}

// ---------------------------------------------------------------------------
// Kernel 0a: fp32 -> bf16 bulk convert (vectorized, 4 elems/thread).
// ---------------------------------------------------------------------------
__global__ void f2b4(const float* __restrict__ in, ushort_t* __restrict__ out, int n4)
{
    const int i = blockIdx.x * 256 + threadIdx.x;
    if (i < n4) {
        float4 f = ((const float4*)in)[i];
        us4 u;
        u[0] = f2bu(f.x); u[1] = f2bu(f.y); u[2] = f2bu(f.z); u[3] = f2bu(f.w);
        ((us4*)out)[i] = u;
    }
}

// ---------------------------------------------------------------------------
// Kernel 0b: dist_emb fp32 [2047,64] -> bf16 [2048,64] (row 2047 zeroed).
// ---------------------------------------------------------------------------
__global__ void conv_E(const float* __restrict__ dist, ushort_t* __restrict__ Eb)
{
    const int idx = blockIdx.x * 256 + threadIdx.x;   // grid 512 -> 131072
    float v = (idx < 2047 * 64) ? dist[idx] : 0.0f;
    Eb[idx] = f2bu(v);
}

// ---------------------------------------------------------------------------
// Kernel 1: QKV projection, MFMA.  C = xb @ W^T (+bias) -> bf16 [B,NH,S,D].
// A=xb [4096,1024] bf16 k-contig, B=W [1024,1024] bf16 k-contig.
// grid (8, 32, 3), block 256 (4 waves, 2x2 of 64x64).  Direct register
// fragment loads (no LDS, no barriers) — layouts verified in attn_mfma.
// ---------------------------------------------------------------------------
__global__ __launch_bounds__(256)
void qkv_mfma(const ushort_t* __restrict__ xb,
              const ushort_t* __restrict__ Wqb, const float* __restrict__ bq,
              const ushort_t* __restrict__ Wkb, const float* __restrict__ bk,
              const ushort_t* __restrict__ Wvb, const float* __restrict__ bv,
              ushort_t* __restrict__ q, ushort_t* __restrict__ k,
              ushort_t* __restrict__ v)
{
    const int which = blockIdx.z;
    const ushort_t* __restrict__ W    = (which == 0) ? Wqb : (which == 1) ? Wkb : Wvb;
    const float*    __restrict__ bias = (which == 0) ? bq  : (which == 1) ? bk  : bv;
    ushort_t*       __restrict__ out  = (which == 0) ? q   : (which == 1) ? k   : v;

    const int tid = threadIdx.x, w = tid >> 6, lane = tid & 63;
    const int quad = lane >> 4, lq = lane & 15;
    const int wm = w >> 1, wn = w & 1;
    const int m0 = blockIdx.y * 128 + wm * 64;
    const int n0 = blockIdx.x * 128 + wn * 64;

    f32x4 acc[4][4];
#pragma unroll
    for (int i = 0; i < 4; i++)
#pragma unroll
        for (int j = 0; j < 4; j++) acc[i][j] = (f32x4){0.f, 0.f, 0.f, 0.f};

    const ushort_t* aB = xb + (size_t)(m0 + lq) * 1024 + quad * 8;
    const ushort_t* bB = W  + (size_t)(n0 + lq) * 1024 + quad * 8;

#pragma unroll 2
    for (int k0 = 0; k0 < 1024; k0 += 32) {
        short8 af[4], bf[4];
#pragma unroll
        for (int i = 0; i < 4; i++) af[i] = *(const short8*)(aB + i * 16 * 1024 + k0);
#pragma unroll
        for (int j = 0; j < 4; j++) bf[j] = *(const short8*)(bB + j * 16 * 1024 + k0);
#pragma unroll
        for (int i = 0; i < 4; i++)
#pragma unroll
            for (int j = 0; j < 4; j++)
                acc[i][j] = MFMA_16x16x32(af[i], bf[j], acc[i][j]);
    }

#pragma unroll
    for (int j = 0; j < 4; j++) {
        const int n  = n0 + j * 16 + lq;      // = h*64 + d
        const int h_ = n >> 6, d_ = n & 63;
        const float bb = bias[n];
#pragma unroll
        for (int i = 0; i < 4; i++) {
#pragma unroll
            for (int g = 0; g < 4; g++) {
                const int m  = m0 + i * 16 + quad * 4 + g;   // = b*S + l
                const int b_ = m >> 10, l = m & 1023;
                out[(((size_t)(b_ * NHH) + h_) * SS + l) * DD + d_] =
                    f2bu(acc[i][j][g] + bb);
            }
        }
    }
}

// ---------------------------------------------------------------------------
// Kernel 2: MFMA flash attention with relative_key_query bias (unchanged
// structure from R6; epilogue now writes bf16 ctx).
// grid (16, 16, 4), block 256.
// ---------------------------------------------------------------------------
__global__ __launch_bounds__(256)
void attn_mfma(const ushort_t* __restrict__ qb, const ushort_t* __restrict__ kb,
               const ushort_t* __restrict__ vb, const ushort_t* __restrict__ Eb,
               const float* __restrict__ mask, ushort_t* __restrict__ ctx)
{
    const int l0 = blockIdx.x * 64;
    const int h  = blockIdx.y, b = blockIdx.z;
    const int tid  = threadIdx.x;
    const int w    = tid >> 6;
    const int lane = tid & 63;
    const int quad = lane >> 4, lq = lane & 15;

    __shared__ __align__(16) ushort_t QEs[64 * 131];
    __shared__ __align__(16) ushort_t KEs[64 * 131];
    __shared__ __align__(16) ushort_t Ps [64 * 72];
    __shared__ __align__(16) ushort_t VTs[64 * 72];

    const ushort_t* qbh = qb + ((size_t)(b * NHH + h) * SS) * DD;
    const ushort_t* kbh = kb + ((size_t)(b * NHH + h) * SS) * DD;
    const ushort_t* vbh = vb + ((size_t)(b * NHH + h) * SS) * DD;

    short8 qa0, qa1;
    {
        const ushort_t* qrow = qbh + (l0 + w * 16 + lq) * DD + quad * 8;
        qa0 = *(const short8*)(qrow);
        qa1 = *(const short8*)(qrow + 32);
    }

    f32x4 Oacc[4];
#pragma unroll
    for (int dt = 0; dt < 4; dt++) Oacc[dt] = (f32x4){0.f, 0.f, 0.f, 0.f};
    float mrow[4] = {-3e38f, -3e38f, -3e38f, -3e38f};
    float lrow[4] = {0.f, 0.f, 0.f, 0.f};

    for (int rt = 0; rt < 16; rt++) {
        const int r0   = rt * 64;
        const int dmin = l0 - r0 + 960;

        __syncthreads();

        for (int s = tid; s < 512; s += 256) {
            const int r = s >> 3, d0 = (s & 7) * 8;
            short8 vv = *(const short8*)(vbh + (r0 + r) * DD + d0);
#pragma unroll
            for (int e = 0; e < 8; e++) VTs[(d0 + e) * 72 + r] = (ushort_t)vv[e];
        }

        short8 kf[4][2];
#pragma unroll
        for (int ct = 0; ct < 4; ct++) {
            const ushort_t* krow = kbh + (r0 + ct * 16 + lq) * DD + quad * 8;
            kf[ct][0] = *(const short8*)(krow);
            kf[ct][1] = *(const short8*)(krow + 32);
        }

#pragma unroll
        for (int tt = 0; tt < 8; tt++) {
            const ushort_t* erow = Eb + (dmin + tt * 16 + lq) * DD + quad * 8;
            short8 eb0 = *(const short8*)(erow);
            short8 eb1 = *(const short8*)(erow + 32);
            f32x4 qe = (f32x4){0.f, 0.f, 0.f, 0.f};
            f32x4 ke = (f32x4){0.f, 0.f, 0.f, 0.f};
            qe = MFMA_16x16x32(qa0, eb0, qe);
            qe = MFMA_16x16x32(qa1, eb1, qe);
            ke = MFMA_16x16x32(kf[w][0], eb0, ke);
            ke = MFMA_16x16x32(kf[w][1], eb1, ke);
#pragma unroll
            for (int g = 0; g < 4; g++) {
                const int row = w * 16 + quad * 4 + g;
                QEs[row * 131 + tt * 16 + lq] = f2bu(qe[g]);
                KEs[row * 131 + tt * 16 + lq] = f2bu(ke[g]);
            }
        }

        f32x4 s1[4];
#pragma unroll
        for (int ct = 0; ct < 4; ct++) {
            f32x4 a = (f32x4){0.f, 0.f, 0.f, 0.f};
            a = MFMA_16x16x32(qa0, kf[ct][0], a);
            a = MFMA_16x16x32(qa1, kf[ct][1], a);
            s1[ct] = a;
        }

        __syncthreads();

        float p[4][4];
        float tmax[4] = {-3e38f, -3e38f, -3e38f, -3e38f};
#pragma unroll
        for (int ct = 0; ct < 4; ct++) {
            const int j_wg = ct * 16 + lq;
            const float mk = mask[b * SS + r0 + j_wg];
#pragma unroll
            for (int g = 0; g < 4; g++) {
                const int i_wg = w * 16 + quad * 4 + g;
                const int t = i_wg - j_wg + 63;
                float s = (s1[ct][g] + bu2f(QEs[i_wg * 131 + t])
                                     + bu2f(KEs[j_wg * 131 + t])) * 0.125f + mk;
                p[ct][g] = s;
                tmax[g] = fmaxf(tmax[g], s);
            }
        }
#pragma unroll
        for (int g = 0; g < 4; g++) {
            float v = tmax[g];
            v = fmaxf(v, __shfl_xor(v, 1));
            v = fmaxf(v, __shfl_xor(v, 2));
            v = fmaxf(v, __shfl_xor(v, 4));
            v = fmaxf(v, __shfl_xor(v, 8));
            tmax[g] = v;
        }
        float psum[4] = {0.f, 0.f, 0.f, 0.f};
        float alpha[4];
#pragma unroll
        for (int g = 0; g < 4; g++) {
            const float mnew = fmaxf(mrow[g], tmax[g]);
            alpha[g] = __expf(mrow[g] - mnew);
            mrow[g] = mnew;
        }
#pragma unroll
        for (int ct = 0; ct < 4; ct++)
#pragma unroll
            for (int g = 0; g < 4; g++) {
                const float e = __expf(p[ct][g] - mrow[g]);
                p[ct][g] = e;
                psum[g] += e;
            }
#pragma unroll
        for (int g = 0; g < 4; g++) {
            float v = psum[g];
            v += __shfl_xor(v, 1);
            v += __shfl_xor(v, 2);
            v += __shfl_xor(v, 4);
            v += __shfl_xor(v, 8);
            lrow[g] = lrow[g] * alpha[g] + v;
        }
#pragma unroll
        for (int dt = 0; dt < 4; dt++)
#pragma unroll
            for (int g = 0; g < 4; g++) Oacc[dt][g] *= alpha[g];
#pragma unroll
        for (int ct = 0; ct < 4; ct++)
#pragma unroll
            for (int g = 0; g < 4; g++)
                Ps[(w * 16 + quad * 4 + g) * 72 + ct * 16 + lq] = f2bu(p[ct][g]);

        __syncthreads();

        short8 pa0, pa1;
        {
            const ushort_t* prow = Ps + (w * 16 + lq) * 72 + quad * 8;
            pa0 = *(const short8*)(prow);
            pa1 = *(const short8*)(prow + 32);
        }
#pragma unroll
        for (int dt = 0; dt < 4; dt++) {
            const ushort_t* vtr = VTs + (dt * 16 + lq) * 72 + quad * 8;
            short8 vb0 = *(const short8*)(vtr);
            short8 vb1 = *(const short8*)(vtr + 32);
            Oacc[dt] = MFMA_16x16x32(pa0, vb0, Oacc[dt]);
            Oacc[dt] = MFMA_16x16x32(pa1, vb1, Oacc[dt]);
        }
    }

#pragma unroll
    for (int g = 0; g < 4; g++) {
        const int l = l0 + w * 16 + quad * 4 + g;
        const float invl = 1.0f / lrow[g];
#pragma unroll
        for (int dt = 0; dt < 4; dt++)
            ctx[(size_t)(b * SS + l) * HH + h * DD + dt * 16 + lq] =
                f2bu(Oacc[dt][g] * invl);
    }
}

// ---------------------------------------------------------------------------
// Kernel 3: output projection, MFMA.  y = ctx @ Wo^T + bo + x  (fp32 out).
// grid (16, 32), block 256 (4 waves, 2x2 of 64x32).  Tile 128m x 64n.
// ---------------------------------------------------------------------------
__global__ __launch_bounds__(256)
void out_proj(const ushort_t* __restrict__ ctx, const ushort_t* __restrict__ Wob,
              const float* __restrict__ bo, const float* __restrict__ x,
              float* __restrict__ y)
{
    const int tid = threadIdx.x, w = tid >> 6, lane = tid & 63;
    const int quad = lane >> 4, lq = lane & 15;
    const int wm = w >> 1, wn = w & 1;
    const int m0 = blockIdx.y * 128 + wm * 64;
    const int n0 = blockIdx.x * 64 + wn * 32;

    f32x4 acc[4][2];
#pragma unroll
    for (int i = 0; i < 4; i++)
#pragma unroll
        for (int j = 0; j < 2; j++) acc[i][j] = (f32x4){0.f, 0.f, 0.f, 0.f};

    const ushort_t* aB = ctx + (size_t)(m0 + lq) * 1024 + quad * 8;
    const ushort_t* bB = Wob + (size_t)(n0 + lq) * 1024 + quad * 8;

#pragma unroll 2
    for (int k0 = 0; k0 < 1024; k0 += 32) {
        short8 af[4], bf[2];
#pragma unroll
        for (int i = 0; i < 4; i++) af[i] = *(const short8*)(aB + i * 16 * 1024 + k0);
#pragma unroll
        for (int j = 0; j < 2; j++) bf[j] = *(const short8*)(bB + j * 16 * 1024 + k0);
#pragma unroll
        for (int i = 0; i < 4; i++)
#pragma unroll
            for (int j = 0; j < 2; j++)
                acc[i][j] = MFMA_16x16x32(af[i], bf[j], acc[i][j]);
    }

#pragma unroll
    for (int j = 0; j < 2; j++) {
        const int n = n0 + j * 16 + lq;
        const float bb = bo[n];
#pragma unroll
        for (int i = 0; i < 4; i++) {
#pragma unroll
            for (int g = 0; g < 4; g++) {
                const int m = m0 + i * 16 + quad * 4 + g;
                y[(size_t)m * 1024 + n] = acc[i][j][g] + bb + x[(size_t)m * 1024 + n];
            }
        }
    }
}

// ---------------------------------------------------------------------------
// Kernel 4: LayerNorm per row (float4), fp32 out.  grid 4096, block 256.
// ---------------------------------------------------------------------------
__global__ void layernorm(const float* __restrict__ y, const float* __restrict__ g,
                          const float* __restrict__ beta, float* __restrict__ out)
{
    const int row = blockIdx.x;
    const int tid = threadIdx.x;

    __shared__ float red[256];
    __shared__ float red2[256];

    const float4 t4 = *(const float4*)(y + (size_t)row * 1024 + tid * 4);
    float s  = t4.x + t4.y + t4.z + t4.w;
    float s2 = t4.x * t4.x + t4.y * t4.y + t4.z * t4.z + t4.w * t4.w;
    red[tid] = s;
    red2[tid] = s2;
    __syncthreads();
    for (int st = 128; st > 0; st >>= 1) {
        if (tid < st) { red[tid] += red[tid + st]; red2[tid] += red2[tid + st]; }
        __syncthreads();
    }
    const float mu  = red[0] * (1.0f / 1024.0f);
    const float var = red2[0] * (1.0f / 1024.0f) - mu * mu;
    const float rs  = rsqrtf(var + 1e-12f);

    const float4 g4 = *(const float4*)(g + tid * 4);
    const float4 b4 = *(const float4*)(beta + tid * 4);
    float4 o;
    o.x = (t4.x - mu) * rs * g4.x + b4.x;
    o.y = (t4.y - mu) * rs * g4.y + b4.y;
    o.z = (t4.z - mu) * rs * g4.z + b4.z;
    o.w = (t4.w - mu) * rs * g4.w + b4.w;
    *(float4*)(out + (size_t)row * 1024 + tid * 4) = o;
}

// ---------------------------------------------------------------------------
extern "C" void kernel_launch(void* const* d_in, const int* in_sizes, int n_in,
                              void* d_out, int out_size, void* d_ws, size_t ws_size,
                              hipStream_t stream)
{
    const float* x    = (const float*)d_in[0];
    const float* mask = (const float*)d_in[1];
    const float* Wq   = (const float*)d_in[2];
    const float* bq   = (const float*)d_in[3];
    const float* Wk   = (const float*)d_in[4];
    const float* bk   = (const float*)d_in[5];
    const float* Wv   = (const float*)d_in[6];
    const float* bv   = (const float*)d_in[7];
    const float* dist = (const float*)d_in[8];
    const float* Wo   = (const float*)d_in[9];
    const float* bo   = (const float*)d_in[10];
    const float* g    = (const float*)d_in[11];
    const float* be   = (const float*)d_in[12];

    // ws bytes (40.25 MB total, <= 44 MB proven-safe):
    //  xb   [ 0M,  8M)   bf16 x
    //  Wqb  [ 8M, 10M) Wkb [10M,12M) Wvb [12M,14M) Wob [14M,16M)
    //  qb   [16M, 24M)  kb [24M, 32M)  vb [32M, 40M)   bf16 heads
    //  Eb   [40M, 40.25M)
    //  y    overlays [16M, 32M) fp32 (qb/kb dead after attn)
    // d_out scratch: ctx bf16 in [0, 8M) until layernorm overwrites.
    char* wsb = (char*)d_ws;
    ushort_t* xb  = (ushort_t*)(wsb);
    ushort_t* Wqb = (ushort_t*)(wsb + ( 8u << 20));
    ushort_t* Wkb = (ushort_t*)(wsb + (10u << 20));
    ushort_t* Wvb = (ushort_t*)(wsb + (12u << 20));
    ushort_t* Wob = (ushort_t*)(wsb + (14u << 20));
    ushort_t* qbu = (ushort_t*)(wsb + (16u << 20));
    ushort_t* kbu = (ushort_t*)(wsb + (24u << 20));
    ushort_t* vbu = (ushort_t*)(wsb + (32u << 20));
    ushort_t* Eb  = (ushort_t*)(wsb + (40u << 20));
    float*    y   = (float*)(wsb + (16u << 20));
    ushort_t* ctxb = (ushort_t*)d_out;

    conv_E<<<512, 256, 0, stream>>>(dist, Eb);
    f2b4<<<4096, 256, 0, stream>>>(x,  xb,  1048576);
    f2b4<<<1024, 256, 0, stream>>>(Wq, Wqb, 262144);
    f2b4<<<1024, 256, 0, stream>>>(Wk, Wkb, 262144);
    f2b4<<<1024, 256, 0, stream>>>(Wv, Wvb, 262144);
    f2b4<<<1024, 256, 0, stream>>>(Wo, Wob, 262144);

    qkv_mfma<<<dim3(8, 32, 3), 256, 0, stream>>>(xb, Wqb, bq, Wkb, bk, Wvb, bv,
                                                 qbu, kbu, vbu);
    attn_mfma<<<dim3(16, 16, 4), 256, 0, stream>>>(qbu, kbu, vbu, Eb, mask, ctxb);
    out_proj<<<dim3(16, 32), 256, 0, stream>>>(ctxb, Wob, bo, x, y);
    layernorm<<<4096, 256, 0, stream>>>(y, g, be, (float*)d_out);
}

// Round 8
// 486.591 us; speedup vs baseline: 11.8211x; 1.3915x over previous
//
#include <hip/hip_runtime.h>
#include <hip/hip_bf16.h>

#define BB 4
#define SS 1024
#define HH 1024
#define NHH 16
#define DD 64
#define MAXPOS 1024

typedef __hip_bfloat16 bf16;
typedef unsigned short ushort_t;
typedef __attribute__((ext_vector_type(8))) short short8;
typedef __attribute__((ext_vector_type(4))) float f32x4;
typedef __attribute__((ext_vector_type(4))) unsigned short us4;

#define MFMA_16x16x32(a, b, c) __builtin_amdgcn_mfma_f32_16x16x32_bf16((a), (b), (c), 0, 0, 0)

__device__ __forceinline__ float bu2f(ushort_t u) {
    union { unsigned int i; float f; } c; c.i = ((unsigned int)u) << 16; return c.f;
}
__device__ __forceinline__ ushort_t f2bu(float f) {
    __hip_bfloat16 h = __float2bfloat16(f);
    return *reinterpret_cast<ushort_t*>(&h);
}

// ---------------------------------------------------------------------------
// Kernel 0: all fp32->bf16 conversions in one launch (x, 4 weights, E).
// Segments in units of float4/us4 groups:
//   x [0, 1048576) | Wq +262144 | Wk | Wv | Wo -> 2097152 | E [.., 2129920)
// E: 2047*64 = 131008 valid floats = 32752 groups; rest zero (row 2047).
// ---------------------------------------------------------------------------
__global__ void conv_all(const float* __restrict__ x,  const float* __restrict__ Wq,
                         const float* __restrict__ Wk, const float* __restrict__ Wv,
                         const float* __restrict__ Wo, const float* __restrict__ dist,
                         ushort_t* __restrict__ xb,  ushort_t* __restrict__ Wqb,
                         ushort_t* __restrict__ Wkb, ushort_t* __restrict__ Wvb,
                         ushort_t* __restrict__ Wob, ushort_t* __restrict__ Eb)
{
    const int i = blockIdx.x * 256 + threadIdx.x;
    const float* src; ushort_t* dst; int off;
    if (i < 1048576)      { src = x;  dst = xb;  off = i; }
    else if (i < 1310720) { src = Wq; dst = Wqb; off = i - 1048576; }
    else if (i < 1572864) { src = Wk; dst = Wkb; off = i - 1310720; }
    else if (i < 1835008) { src = Wv; dst = Wvb; off = i - 1572864; }
    else if (i < 2097152) { src = Wo; dst = Wob; off = i - 1835008; }
    else if (i < 2129920) {
        const int j = i - 2097152;
        float4 f = (j < 32752) ? ((const float4*)dist)[j] : make_float4(0.f, 0.f, 0.f, 0.f);
        us4 u;
        u[0] = f2bu(f.x); u[1] = f2bu(f.y); u[2] = f2bu(f.z); u[3] = f2bu(f.w);
        ((us4*)Eb)[j] = u;
        return;
    } else return;
    float4 f = ((const float4*)src)[off];
    us4 u;
    u[0] = f2bu(f.x); u[1] = f2bu(f.y); u[2] = f2bu(f.z); u[3] = f2bu(f.w);
    ((us4*)dst)[off] = u;
}

// ---------------------------------------------------------------------------
// Kernel 1: QKV projection, MFMA.  C = xb @ W^T (+bias).
//   Q -> [B,NH,S,D], PRE-SCALED by 0.125 (exact in bf16)
//   K -> [B,NH,S,D]
//   V -> [B,NH,D,S]  (transposed: PV A-operand reads rows of V^T directly)
// grid (8, 32, 3), block 256 (4 waves, 2x2 of 64x64).
// ---------------------------------------------------------------------------
__global__ __launch_bounds__(256)
void qkv_mfma(const ushort_t* __restrict__ xb,
              const ushort_t* __restrict__ Wqb, const float* __restrict__ bq,
              const ushort_t* __restrict__ Wkb, const float* __restrict__ bk,
              const ushort_t* __restrict__ Wvb, const float* __restrict__ bv,
              ushort_t* __restrict__ q, ushort_t* __restrict__ k,
              ushort_t* __restrict__ vt)
{
    const int which = blockIdx.z;
    const ushort_t* __restrict__ W    = (which == 0) ? Wqb : (which == 1) ? Wkb : Wvb;
    const float*    __restrict__ bias = (which == 0) ? bq  : (which == 1) ? bk  : bv;

    const int tid = threadIdx.x, w = tid >> 6, lane = tid & 63;
    const int quad = lane >> 4, lq = lane & 15;
    const int wm = w >> 1, wn = w & 1;
    const int m0 = blockIdx.y * 128 + wm * 64;
    const int n0 = blockIdx.x * 128 + wn * 64;

    f32x4 acc[4][4];
#pragma unroll
    for (int i = 0; i < 4; i++)
#pragma unroll
        for (int j = 0; j < 4; j++) acc[i][j] = (f32x4){0.f, 0.f, 0.f, 0.f};

    const ushort_t* aB = xb + (size_t)(m0 + lq) * 1024 + quad * 8;
    const ushort_t* bB = W  + (size_t)(n0 + lq) * 1024 + quad * 8;

#pragma unroll 2
    for (int k0 = 0; k0 < 1024; k0 += 32) {
        short8 af[4], bf[4];
#pragma unroll
        for (int i = 0; i < 4; i++) af[i] = *(const short8*)(aB + i * 16 * 1024 + k0);
#pragma unroll
        for (int j = 0; j < 4; j++) bf[j] = *(const short8*)(bB + j * 16 * 1024 + k0);
#pragma unroll
        for (int i = 0; i < 4; i++)
#pragma unroll
            for (int j = 0; j < 4; j++)
                acc[i][j] = MFMA_16x16x32(af[i], bf[j], acc[i][j]);
    }

    if (which == 2) {
        // V^T: out[((b*NH+h)*D + d)*S + l], l = m-index (contiguous in g)
#pragma unroll
        for (int j = 0; j < 4; j++) {
            const int n  = n0 + j * 16 + lq;
            const int h_ = n >> 6, d_ = n & 63;
            const float bb = bias[n];
#pragma unroll
            for (int i = 0; i < 4; i++) {
                const int m  = m0 + i * 16 + quad * 4;   // g=0 row
                const int b_ = m >> 10, l = m & 1023;
                us4 pv;
#pragma unroll
                for (int g = 0; g < 4; g++) pv[g] = f2bu(acc[i][j][g] + bb);
                *(us4*)(vt + (((size_t)(b_ * NHH) + h_) * DD + d_) * SS + l) = pv;
            }
        }
    } else {
        ushort_t* __restrict__ out = (which == 0) ? q : k;
        const float sc = (which == 0) ? 0.125f : 1.0f;
#pragma unroll
        for (int j = 0; j < 4; j++) {
            const int n  = n0 + j * 16 + lq;
            const int h_ = n >> 6, d_ = n & 63;
            const float bb = bias[n];
#pragma unroll
            for (int i = 0; i < 4; i++) {
#pragma unroll
                for (int g = 0; g < 4; g++) {
                    const int m  = m0 + i * 16 + quad * 4 + g;
                    const int b_ = m >> 10, l = m & 1023;
                    out[(((size_t)(b_ * NHH) + h_) * SS + l) * DD + d_] =
                        f2bu((acc[i][j][g] + bb) * sc);
                }
            }
        }
    }
}

// ---------------------------------------------------------------------------
// Kernel 2: MFMA flash attention, S^T formulation.
//   S^T = K Q^T  (Q pre-scaled by 1/8)  -> C[r=quad*4+g][l=lq] per 16x16
//   QE = Q E^T, KE' = (K E^T)*0.125 + mask  -> transposed packed LDS stores
//   score = S^T + QE[l][t] + KE'[r][t],  t = l_loc - r_loc + 63
//   softmax over r (per-lane scalar state, cross-quad shuffles)
//   P^T packs straight from C-registers -> wave-local LDS -> B-operand
//   O^T += V^T P^T  (V^T A-frags direct from global)
// grid (16, 16, 4), block 256.
// ---------------------------------------------------------------------------
__global__ __launch_bounds__(256)
void attn_mfma(const ushort_t* __restrict__ qb, const ushort_t* __restrict__ kb,
               const ushort_t* __restrict__ vt, const ushort_t* __restrict__ Eb,
               const float* __restrict__ mask, ushort_t* __restrict__ ctx)
{
    const int l0 = blockIdx.x * 64;
    const int h  = blockIdx.y, b = blockIdx.z;
    const int tid  = threadIdx.x;
    const int w    = tid >> 6;
    const int lane = tid & 63;
    const int quad = lane >> 4, lq = lane & 15;

    // LDS: 2*128*68*2 + 64*72*2 = 44,032 B
    __shared__ __align__(16) ushort_t QEsT[128 * 68];   // [t][l]
    __shared__ __align__(16) ushort_t KEsT[128 * 68];   // [t][r]
    __shared__ __align__(16) ushort_t PsT [64 * 72];    // [l][r]

    const ushort_t* qbh = qb + (size_t)(b * NHH + h) * SS * DD;
    const ushort_t* kbh = kb + (size_t)(b * NHH + h) * SS * DD;
    const ushort_t* vth = vt + (size_t)(b * NHH + h) * DD * SS;   // [d][s]

    // Q B-frag (pre-scaled): rows l = l0 + w*16 + lq
    short8 qa0, qa1;
    {
        const ushort_t* p = qbh + (l0 + w * 16 + lq) * DD + quad * 8;
        qa0 = *(const short8*)p;
        qa1 = *(const short8*)(p + 32);
    }
    const int l_loc = w * 16 + lq;

    f32x4 Oacc[4];
#pragma unroll
    for (int dt = 0; dt < 4; dt++) Oacc[dt] = (f32x4){0.f, 0.f, 0.f, 0.f};
    float mrow = -3e38f, lrow = 0.f;

    for (int rt = 0; rt < 16; rt++) {
        const int r0   = rt * 64;
        const int dmin = l0 - r0 + 960;

        // K fragments (rows r0 + ct*16 + lq)
        short8 kf0[4], kf1[4];
#pragma unroll
        for (int ct = 0; ct < 4; ct++) {
            const ushort_t* p = kbh + (r0 + ct * 16 + lq) * DD + quad * 8;
            kf0[ct] = *(const short8*)p;
            kf1[ct] = *(const short8*)(p + 32);
        }
        // mask values for KE fold (rows r = r0 + w*16 + quad*4 + g)
        float mk[4];
#pragma unroll
        for (int g = 0; g < 4; g++) mk[g] = mask[b * SS + r0 + w * 16 + quad * 4 + g];

        __syncthreads();   // prior tile's QEsT/KEsT reads done

        // --- QE / KE' via MFMA, transposed packed stores ---
#pragma unroll
        for (int tt = 0; tt < 8; tt++) {
            const ushort_t* ep = Eb + (size_t)(dmin + tt * 16 + lq) * DD + quad * 8;
            short8 e0 = *(const short8*)ep;
            short8 e1 = *(const short8*)(ep + 32);
            f32x4 qe = (f32x4){0.f, 0.f, 0.f, 0.f};
            f32x4 ke = (f32x4){0.f, 0.f, 0.f, 0.f};
            qe = MFMA_16x16x32(qa0, e0, qe);
            qe = MFMA_16x16x32(qa1, e1, qe);
            ke = MFMA_16x16x32(kf0[w], e0, ke);
            ke = MFMA_16x16x32(kf1[w], e1, ke);
            us4 pq, pk;
#pragma unroll
            for (int g = 0; g < 4; g++) {
                pq[g] = f2bu(qe[g]);                       // already /8 via Q
                pk[g] = f2bu(ke[g] * 0.125f + mk[g]);      // mask folded in
            }
            const int trow = tt * 16 + lq;
            *(us4*)&QEsT[trow * 68 + w * 16 + quad * 4] = pq;
            *(us4*)&KEsT[trow * 68 + w * 16 + quad * 4] = pk;
        }

        // --- S^T = K Q^T for this wave's l-block ---
        f32x4 st[4];
#pragma unroll
        for (int ct = 0; ct < 4; ct++) {
            f32x4 a = (f32x4){0.f, 0.f, 0.f, 0.f};
            a = MFMA_16x16x32(kf0[ct], qa0, a);
            a = MFMA_16x16x32(kf1[ct], qa1, a);
            st[ct] = a;
        }

        __syncthreads();   // QEsT/KEsT visible (KEsT is cross-wave)

        // --- scores + online softmax (per-lane l fixed) ---
        float p[4][4];
        float tmax = -3e38f;
#pragma unroll
        for (int ct = 0; ct < 4; ct++) {
#pragma unroll
            for (int g = 0; g < 4; g++) {
                const int r_loc = ct * 16 + quad * 4 + g;
                const int t = l_loc - r_loc + 63;      // [0,126]
                float s = st[ct][g] + bu2f(QEsT[t * 68 + l_loc])
                                    + bu2f(KEsT[t * 68 + r_loc]);
                p[ct][g] = s;
                tmax = fmaxf(tmax, s);
            }
        }
        tmax = fmaxf(tmax, __shfl_xor(tmax, 16));
        tmax = fmaxf(tmax, __shfl_xor(tmax, 32));
        const float mnew  = fmaxf(mrow, tmax);
        const float alpha = __expf(mrow - mnew);
        mrow = mnew;
        float psum = 0.f;
#pragma unroll
        for (int ct = 0; ct < 4; ct++)
#pragma unroll
            for (int g = 0; g < 4; g++) {
                const float e = __expf(p[ct][g] - mrow);
                p[ct][g] = e;
                psum += e;
            }
        psum += __shfl_xor(psum, 16);
        psum += __shfl_xor(psum, 32);
        lrow = lrow * alpha + psum;
#pragma unroll
        for (int dt = 0; dt < 4; dt++)
#pragma unroll
            for (int g = 0; g < 4; g++) Oacc[dt][g] *= alpha;

        // --- P^T -> LDS (wave-local rows, packed) ---
#pragma unroll
        for (int ct = 0; ct < 4; ct++) {
            us4 pp;
#pragma unroll
            for (int g = 0; g < 4; g++) pp[g] = f2bu(p[ct][g]);
            *(us4*)&PsT[l_loc * 72 + ct * 16 + quad * 4] = pp;
        }

        // --- O^T += V^T P^T (no barrier: PsT rows are wave-local) ---
#pragma unroll
        for (int c = 0; c < 2; c++) {
            short8 pb = *(const short8*)&PsT[l_loc * 72 + c * 32 + quad * 8];
#pragma unroll
            for (int dt = 0; dt < 4; dt++) {
                const ushort_t* vp = vth + (size_t)(dt * 16 + lq) * SS
                                         + r0 + c * 32 + quad * 8;
                short8 va = *(const short8*)vp;
                Oacc[dt] = MFMA_16x16x32(va, pb, Oacc[dt]);
            }
        }
    }

    // --- epilogue: ctx[b, l, h*64 + d] bf16, packed us4 over d ---
    const float invl = 1.0f / lrow;
    ushort_t* cbase = ctx + (size_t)(b * SS + l0 + w * 16 + lq) * HH + h * DD;
#pragma unroll
    for (int dt = 0; dt < 4; dt++) {
        us4 po;
#pragma unroll
        for (int g = 0; g < 4; g++) po[g] = f2bu(Oacc[dt][g] * invl);
        *(us4*)(cbase + dt * 16 + quad * 4) = po;
    }
}

// ---------------------------------------------------------------------------
// Kernel 3: output projection, MFMA.  y = ctx @ Wo^T + bo + x  (fp32 out).
// grid (16, 32), block 256 (4 waves, 2x2 of 64x32).
// ---------------------------------------------------------------------------
__global__ __launch_bounds__(256)
void out_proj(const ushort_t* __restrict__ ctx, const ushort_t* __restrict__ Wob,
              const float* __restrict__ bo, const float* __restrict__ x,
              float* __restrict__ y)
{
    const int tid = threadIdx.x, w = tid >> 6, lane = tid & 63;
    const int quad = lane >> 4, lq = lane & 15;
    const int wm = w >> 1, wn = w & 1;
    const int m0 = blockIdx.y * 128 + wm * 64;
    const int n0 = blockIdx.x * 64 + wn * 32;

    f32x4 acc[4][2];
#pragma unroll
    for (int i = 0; i < 4; i++)
#pragma unroll
        for (int j = 0; j < 2; j++) acc[i][j] = (f32x4){0.f, 0.f, 0.f, 0.f};

    const ushort_t* aB = ctx + (size_t)(m0 + lq) * 1024 + quad * 8;
    const ushort_t* bB = Wob + (size_t)(n0 + lq) * 1024 + quad * 8;

#pragma unroll 2
    for (int k0 = 0; k0 < 1024; k0 += 32) {
        short8 af[4], bf[2];
#pragma unroll
        for (int i = 0; i < 4; i++) af[i] = *(const short8*)(aB + i * 16 * 1024 + k0);
#pragma unroll
        for (int j = 0; j < 2; j++) bf[j] = *(const short8*)(bB + j * 16 * 1024 + k0);
#pragma unroll
        for (int i = 0; i < 4; i++)
#pragma unroll
            for (int j = 0; j < 2; j++)
                acc[i][j] = MFMA_16x16x32(af[i], bf[j], acc[i][j]);
    }

#pragma unroll
    for (int j = 0; j < 2; j++) {
        const int n = n0 + j * 16 + lq;
        const float bb = bo[n];
#pragma unroll
        for (int i = 0; i < 4; i++) {
#pragma unroll
            for (int g = 0; g < 4; g++) {
                const int m = m0 + i * 16 + quad * 4 + g;
                y[(size_t)m * 1024 + n] = acc[i][j][g] + bb + x[(size_t)m * 1024 + n];
            }
        }
    }
}

// ---------------------------------------------------------------------------
// Kernel 4: LayerNorm per row (float4), fp32 out.  grid 4096, block 256.
// ---------------------------------------------------------------------------
__global__ void layernorm(const float* __restrict__ y, const float* __restrict__ g,
                          const float* __restrict__ beta, float* __restrict__ out)
{
    const int row = blockIdx.x;
    const int tid = threadIdx.x;

    __shared__ float red[256];
    __shared__ float red2[256];

    const float4 t4 = *(const float4*)(y + (size_t)row * 1024 + tid * 4);
    float s  = t4.x + t4.y + t4.z + t4.w;
    float s2 = t4.x * t4.x + t4.y * t4.y + t4.z * t4.z + t4.w * t4.w;
    red[tid] = s;
    red2[tid] = s2;
    __syncthreads();
    for (int st = 128; st > 0; st >>= 1) {
        if (tid < st) { red[tid] += red[tid + st]; red2[tid] += red2[tid + st]; }
        __syncthreads();
    }
    const float mu  = red[0] * (1.0f / 1024.0f);
    const float var = red2[0] * (1.0f / 1024.0f) - mu * mu;
    const float rs  = rsqrtf(var + 1e-12f);

    const float4 g4 = *(const float4*)(g + tid * 4);
    const float4 b4 = *(const float4*)(beta + tid * 4);
    float4 o;
    o.x = (t4.x - mu) * rs * g4.x + b4.x;
    o.y = (t4.y - mu) * rs * g4.y + b4.y;
    o.z = (t4.z - mu) * rs * g4.z + b4.z;
    o.w = (t4.w - mu) * rs * g4.w + b4.w;
    *(float4*)(out + (size_t)row * 1024 + tid * 4) = o;
}

// ---------------------------------------------------------------------------
extern "C" void kernel_launch(void* const* d_in, const int* in_sizes, int n_in,
                              void* d_out, int out_size, void* d_ws, size_t ws_size,
                              hipStream_t stream)
{
    const float* x    = (const float*)d_in[0];
    const float* mask = (const float*)d_in[1];
    const float* Wq   = (const float*)d_in[2];
    const float* bq   = (const float*)d_in[3];
    const float* Wk   = (const float*)d_in[4];
    const float* bk   = (const float*)d_in[5];
    const float* Wv   = (const float*)d_in[6];
    const float* bv   = (const float*)d_in[7];
    const float* dist = (const float*)d_in[8];
    const float* Wo   = (const float*)d_in[9];
    const float* bo   = (const float*)d_in[10];
    const float* g    = (const float*)d_in[11];
    const float* be   = (const float*)d_in[12];

    // ws bytes (40.25 MB, <= 44 MB proven-safe):
    //  xb [0,8M) | Wqb [8,10M) Wkb [10,12M) Wvb [12,14M) Wob [14,16M)
    //  qb [16,24M) kb [24,32M) vt [32,40M) (V^T [B,NH,D,S]) | Eb [40,40.25M)
    //  y fp32 overlays [16,32M) (qb/kb dead after attn)
    // d_out scratch: ctx bf16 until layernorm overwrites fp32.
    char* wsb = (char*)d_ws;
    ushort_t* xb  = (ushort_t*)(wsb);
    ushort_t* Wqb = (ushort_t*)(wsb + ( 8u << 20));
    ushort_t* Wkb = (ushort_t*)(wsb + (10u << 20));
    ushort_t* Wvb = (ushort_t*)(wsb + (12u << 20));
    ushort_t* Wob = (ushort_t*)(wsb + (14u << 20));
    ushort_t* qbu = (ushort_t*)(wsb + (16u << 20));
    ushort_t* kbu = (ushort_t*)(wsb + (24u << 20));
    ushort_t* vtb = (ushort_t*)(wsb + (32u << 20));
    ushort_t* Eb  = (ushort_t*)(wsb + (40u << 20));
    float*    y   = (float*)(wsb + (16u << 20));
    ushort_t* ctxb = (ushort_t*)d_out;

    conv_all<<<8320, 256, 0, stream>>>(x, Wq, Wk, Wv, Wo, dist,
                                       xb, Wqb, Wkb, Wvb, Wob, Eb);
    qkv_mfma<<<dim3(8, 32, 3), 256, 0, stream>>>(xb, Wqb, bq, Wkb, bk, Wvb, bv,
                                                 qbu, kbu, vtb);
    attn_mfma<<<dim3(16, 16, 4), 256, 0, stream>>>(qbu, kbu, vtb, Eb, mask, ctxb);
    out_proj<<<dim3(16, 32), 256, 0, stream>>>(ctxb, Wob, bo, x, y);
    layernorm<<<4096, 256, 0, stream>>>(y, g, be, (float*)d_out);
}